// Round 4
// baseline (80.212 us; speedup 1.0000x reference)
//
#include <hip/hip_runtime.h>

// Problem constants (fixed by setup_inputs)
#define B  8
#define D  192
#define TY 8192
#define TX 1024

typedef float f4 __attribute__((ext_vector_type(4)));

static constexpr long long ATTN_N = (long long)B * TY * TX;      // 67,108,864 floats
static constexpr long long W_N    = (long long)B * TX;           // 8,192
static constexpr long long MPE_N  = (long long)B * D * TY;       // 12,582,912

static constexpr int TX4 = TX / 4;            // 256 f4 per source/attn row
static constexpr int TY4 = TY / 4;            // 2048 f4 per mpe row

static constexpr int A4_END  = (int)(ATTN_N / 4);          // 16,777,216
static constexpr int AB_END  = (int)((ATTN_N + W_N) / 4);  // 16,779,264
static constexpr long long C_BASE4 = (ATTN_N + W_N) / 4;   // 16,779,264

static constexpr int C_BLOCKS = B * D;        // 1536 (one per (b,d) row) — dispatched FIRST
static constexpr int A_BLOCKS = 1536;         // grid-stride sweep of attn + w regions
static constexpr int SWEEP_STRIDE = A_BLOCKS * 256;   // 393,216 f4 per sweep step

// Single kernel.
//  Blocks [0,1536):      C region. Block = one (b,d): read m_p row + logs_p row (8 KB),
//                        reduce, write both 32 KB output rows (zeros + hot element).
//                        Low block IDs -> reads issue during launch ramp.
//  Blocks [1536,3072):   uniform grid-stride sweep of attn + w regions (fillBuffer-style
//                        address pattern, plain cached dwordx4 stores).
__global__ __launch_bounds__(256) void vits_fused2(
    const f4* __restrict__ mp4,
    const f4* __restrict__ lp4,
    const int* __restrict__ ylen,
    f4* __restrict__ out4)
{
    const int blk = blockIdx.x;
    const int tid = threadIdx.x;

    if (blk < C_BLOCKS) {
        // ---- m_p_exp / logs_p_exp rows ----
        const int w   = blk;                 // source row (b,d), uniform
        const int b   = w / D;               // scalar div by 192 (magic-mul)
        const int yh  = ylen[b] - 1;         // in [4095, 8191]
        const int hot = yh >> 2;             // hot f4 index within the row
        const int sub = yh & 3;

        f4 am = mp4[(long long)w * TX4 + tid];
        f4 al = lp4[(long long)w * TX4 + tid];
        float sm = am.x + am.y + am.z + am.w;
        float sl = al.x + al.y + al.z + al.w;
#pragma unroll
        for (int off = 32; off; off >>= 1) {
            sm += __shfl_xor(sm, off);
            sl += __shfl_xor(sl, off);
        }
        __shared__ float redm[4], redl[4];
        if ((tid & 63) == 0) { redm[tid >> 6] = sm; redl[tid >> 6] = sl; }
        __syncthreads();
        sm = redm[0] + redm[1] + redm[2] + redm[3];
        sl = redl[0] + redl[1] + redl[2] + redl[3];

        const long long mbase = C_BASE4 + (long long)w * TY4;
        const long long lbase = C_BASE4 + (long long)(C_BLOCKS + w) * TY4;
#pragma unroll
        for (int it = 0; it < TY4 / 256; ++it) {        // 8 iterations
            const int j = it * 256 + tid;
            f4 vm = {0.f, 0.f, 0.f, 0.f};
            f4 vl = {0.f, 0.f, 0.f, 0.f};
            if (j == hot) {                              // one thread per row
                vm.x = (sub == 0) ? sm : 0.f;  vl.x = (sub == 0) ? sl : 0.f;
                vm.y = (sub == 1) ? sm : 0.f;  vl.y = (sub == 1) ? sl : 0.f;
                vm.z = (sub == 2) ? sm : 0.f;  vl.z = (sub == 2) ? sl : 0.f;
                vm.w = (sub == 3) ? sm : 0.f;  vl.w = (sub == 3) ? sl : 0.f;
            }
            out4[mbase + j] = vm;
            out4[lbase + j] = vl;
        }
    } else {
        // ---- attn + w regions: uniform sweep ----
        __shared__ int yhs[B];
        if (tid < B) yhs[tid] = ylen[tid] - 1;
        __syncthreads();

        int i = (blk - C_BLOCKS) * 256 + tid;
#pragma unroll 4
        for (; i < AB_END; i += SWEEP_STRIDE) {
            float s;
            if (i < A4_END) {
                const int y = (i >> 8) & (TY - 1);   // TX4 = 2^8
                const int b = i >> 21;               // TY*TX4 = 2^21
                s = (y == yhs[b]) ? 1.0f : 0.0f;     // LDS broadcast (wave-uniform addr)
            } else {
                s = 1.0f;                            // w region
            }
            f4 v = {s, s, s, s};
            out4[i] = v;
        }
    }
}

extern "C" void kernel_launch(void* const* d_in, const int* in_sizes, int n_in,
                              void* d_out, int out_size, void* d_ws, size_t ws_size,
                              hipStream_t stream) {
    // inputs: 0=z_p (unused), 1=m_p, 2=logs_p, 3=x_lengths (unused), 4=y_lengths
    const f4* mp4   = (const f4*)d_in[1];
    const f4* lp4   = (const f4*)d_in[2];
    const int* ylen = (const int*)d_in[4];
    f4* out4 = (f4*)d_out;

    vits_fused2<<<C_BLOCKS + A_BLOCKS, 256, 0, stream>>>(mp4, lp4, ylen, out4);
}

// Round 5
// 73.487 us; speedup vs baseline: 1.0915x; 1.0915x over previous
//
#include <hip/hip_runtime.h>

// Problem constants (fixed by setup_inputs)
#define B  8
#define D  192
#define TY 8192
#define TX 1024

typedef float f4 __attribute__((ext_vector_type(4)));

static constexpr long long ATTN_N = (long long)B * TY * TX;      // 67,108,864 floats
static constexpr long long W_N    = (long long)B * TX;           // 8,192
static constexpr long long MPE_N  = (long long)B * D * TY;       // 12,582,912

static constexpr int TX4 = TX / 4;                    // 256 f4 per source/attn row
static constexpr int TY4 = TY / 4;                    // 2048 f4 per mpe row
static constexpr long long W_BASE4 = ATTN_N / 4;      // 16,777,216
static constexpr long long C_BASE4 = (ATTN_N + W_N) / 4;

static constexpr int NBLK   = 2048;                   // exactly 8 blocks/CU, one dispatch round
static constexpr int NC     = B * D;                  // 1536 blocks also own one (b,d) row pair
static constexpr int ROWS_A = 32;                     // attn rows per block (2048*32 = 8*8192)

// One kernel, 2048 uniform blocks.
//  Every block: 32 contiguous attn rows of one batch (128 KB of stores, value uniform/row).
//  Blocks [0,1536): additionally one (b,d) row pair — loads issued BEFORE the attn burst
//                   (latency hidden), reduced after, then 64 KB of mpe-row stores.
//  Block 2047:      additionally the 32 KB w region (all ones).
__global__ __launch_bounds__(256) void vits_fused3(
    const f4* __restrict__ mp4,
    const f4* __restrict__ lp4,
    const int* __restrict__ ylen,
    f4* __restrict__ out4)
{
    const int blk = blockIdx.x;
    const int tid = threadIdx.x;
    const bool hasC = (blk < NC);

    // ---- issue source-row loads first (results consumed after the attn burst) ----
    f4 am = {0.f, 0.f, 0.f, 0.f}, al = {0.f, 0.f, 0.f, 0.f};
    if (hasC) {
        am = mp4[(long long)blk * TX4 + tid];
        al = lp4[(long long)blk * TX4 + tid];
    }

    // ---- attn region: 32 full rows, wave-uniform value per row ----
    const int b  = blk >> 8;                          // 256 blocks per batch
    const int y0 = (blk & 255) * ROWS_A;
    const int yh_a = ylen[b] - 1;                     // scalar load
    const long long abase = ((long long)b << 21) + (long long)y0 * TX4 + tid;
#pragma unroll
    for (int r = 0; r < ROWS_A; ++r) {
        const float s = (y0 + r == yh_a) ? 1.0f : 0.0f;
        f4 v = {s, s, s, s};
        __builtin_nontemporal_store(v, &out4[abase + (long long)r * TX4]);
    }

    // ---- w region: all ones (one block) ----
    if (blk == NBLK - 1) {
        f4 one = {1.f, 1.f, 1.f, 1.f};
#pragma unroll
        for (int r = 0; r < 8; ++r)
            __builtin_nontemporal_store(one, &out4[W_BASE4 + r * 256 + tid]);
    }

    // ---- mpe rows: reduce the pre-issued loads, write both 32 KB rows ----
    if (hasC) {
        float sm = am.x + am.y + am.z + am.w;
        float sl = al.x + al.y + al.z + al.w;
#pragma unroll
        for (int off = 32; off; off >>= 1) {
            sm += __shfl_xor(sm, off);
            sl += __shfl_xor(sl, off);
        }
        __shared__ float redm[4], redl[4];
        if ((tid & 63) == 0) { redm[tid >> 6] = sm; redl[tid >> 6] = sl; }
        __syncthreads();
        sm = redm[0] + redm[1] + redm[2] + redm[3];
        sl = redl[0] + redl[1] + redl[2] + redl[3];

        const int bs  = blk / D;                      // source batch (uniform)
        const int yh  = ylen[bs] - 1;                 // in [4095, 8191]
        const int hot = yh >> 2;
        const int sub = yh & 3;

        const long long mbase = C_BASE4 + (long long)blk * TY4;
        const long long lbase = C_BASE4 + (long long)(NC + blk) * TY4;
#pragma unroll
        for (int it = 0; it < TY4 / 256; ++it) {      // 8 iterations x 2 rows
            const int j = it * 256 + tid;
            f4 vm = {0.f, 0.f, 0.f, 0.f};
            f4 vl = {0.f, 0.f, 0.f, 0.f};
            if (j == hot) {                           // one thread per row
                vm.x = (sub == 0) ? sm : 0.f;  vl.x = (sub == 0) ? sl : 0.f;
                vm.y = (sub == 1) ? sm : 0.f;  vl.y = (sub == 1) ? sl : 0.f;
                vm.z = (sub == 2) ? sm : 0.f;  vl.z = (sub == 2) ? sl : 0.f;
                vm.w = (sub == 3) ? sm : 0.f;  vl.w = (sub == 3) ? sl : 0.f;
            }
            __builtin_nontemporal_store(vm, &out4[mbase + j]);
            __builtin_nontemporal_store(vl, &out4[lbase + j]);
        }
    }
}

extern "C" void kernel_launch(void* const* d_in, const int* in_sizes, int n_in,
                              void* d_out, int out_size, void* d_ws, size_t ws_size,
                              hipStream_t stream) {
    // inputs: 0=z_p (unused), 1=m_p, 2=logs_p, 3=x_lengths (unused), 4=y_lengths
    const f4* mp4   = (const f4*)d_in[1];
    const f4* lp4   = (const f4*)d_in[2];
    const int* ylen = (const int*)d_in[4];
    f4* out4 = (f4*)d_out;

    vits_fused3<<<NBLK, 256, 0, stream>>>(mp4, lp4, ylen, out4);
}